// Round 2
// 274.491 us; speedup vs baseline: 1.0263x; 1.0263x over previous
//
#include <hip/hip_runtime.h>
#include <cmath>

constexpr int S_LEN = 2048;
constexpr float EPS = 1e-8f;

typedef unsigned uvec32 __attribute__((ext_vector_type(32)));

__device__ __forceinline__ float fin(float v) { return isfinite(v) ? v : 0.0f; }

__device__ __forceinline__ unsigned f2o_bits(unsigned u) {
    return (u & 0x80000000u) ? ~u : (u | 0x80000000u);
}
__device__ __forceinline__ float o2f(unsigned u) {
    return __uint_as_float((u & 0x80000000u) ? (u ^ 0x80000000u) : ~u);
}

// ---- DPP helpers (ctrl/rmask are ICEs via template params) ----
template <int Ctrl, int Rmask>
__device__ __forceinline__ int dpp_zero_i(int x) {
    return __builtin_amdgcn_update_dpp(0, x, Ctrl, Rmask, 0xF, true);
}
template <int Ctrl>
__device__ __forceinline__ int dpp_keep_i(int x) {
    return __builtin_amdgcn_update_dpp(x, x, Ctrl, 0xF, 0xF, false);
}
__device__ __forceinline__ int wred_add_i(int v) {
    v += dpp_zero_i<0xB1, 0xF>(v);
    v += dpp_zero_i<0x4E, 0xF>(v);
    v += dpp_zero_i<0x114, 0xF>(v);
    v += dpp_zero_i<0x118, 0xF>(v);
    v += dpp_zero_i<0x142, 0xA>(v);
    v += dpp_zero_i<0x143, 0xC>(v);
    return __builtin_amdgcn_readlane(v, 63);
}
__device__ __forceinline__ float wred_add_f(float v) {
    #define ADDF(CT, RM) v += __uint_as_float((unsigned)dpp_zero_i<CT, RM>((int)__float_as_uint(v)))
    ADDF(0xB1, 0xF); ADDF(0x4E, 0xF); ADDF(0x114, 0xF);
    ADDF(0x118, 0xF); ADDF(0x142, 0xA); ADDF(0x143, 0xC);
    #undef ADDF
    return __uint_as_float((unsigned)__builtin_amdgcn_readlane((int)__float_as_uint(v), 63));
}
__device__ __forceinline__ float wred_min_f(float v) {
    #define MINF(CT) v = fminf(v, __uint_as_float((unsigned)dpp_keep_i<CT>((int)__float_as_uint(v))))
    MINF(0xB1); MINF(0x4E); MINF(0x114); MINF(0x118); MINF(0x142); MINF(0x143);
    #undef MINF
    return __uint_as_float((unsigned)__builtin_amdgcn_readlane((int)__float_as_uint(v), 63));
}
__device__ __forceinline__ float wred_max_f(float v) {
    #define MAXF(CT) v = fmaxf(v, __uint_as_float((unsigned)dpp_keep_i<CT>((int)__float_as_uint(v))))
    MAXF(0xB1); MAXF(0x4E); MAXF(0x114); MAXF(0x118); MAXF(0x142); MAXF(0x143);
    #undef MAXF
    return __uint_as_float((unsigned)__builtin_amdgcn_readlane((int)__float_as_uint(v), 63));
}
__device__ __forceinline__ unsigned wred_umin(unsigned v) {
    #define MINU(CT) { unsigned t = (unsigned)dpp_keep_i<CT>((int)v); v = v < t ? v : t; }
    MINU(0xB1) MINU(0x4E) MINU(0x114) MINU(0x118) MINU(0x142) MINU(0x143)
    #undef MINU
    return (unsigned)__builtin_amdgcn_readlane((int)v, 63);
}
__device__ __forceinline__ float readlane_f(float x, int l) {
    return __uint_as_float((unsigned)__builtin_amdgcn_readlane((int)__float_as_uint(x), l));
}

// Hacker's Delight 32x32 bit transpose (anti-diagonal; involution).
__device__ __forceinline__ void transpose32(uvec32& A) {
    #pragma unroll
    for (int j = 16; j; j >>= 1) {
        unsigned m = (j == 16) ? 0x0000FFFFu : (j == 8) ? 0x00FF00FFu
                   : (j == 4) ? 0x0F0F0F0Fu : (j == 2) ? 0x33333333u : 0x55555555u;
        #pragma unroll
        for (int k = 0; k < 32; k++) {
            if (!(k & j)) {
                unsigned t = (A[k] ^ (A[k | j] >> j)) & m;
                A[k] = A[k] ^ t;
                A[k | j] = A[k | j] ^ (t << j);
            }
        }
    }
}

#define VF(e) __uint_as_float(a[e])

// ============ K0: transpose weights once into d_ws ============
// wt[0:1280)    = W1T  (20 x 64):  W1T[k*64+j]  = W1[j*20+k]
// wt[1280:9472) = W2T  (64 x 128): W2T[k*128+o] = W2[o*64+k]
__global__ __launch_bounds__(256) void transpose_w_kernel(
    const float* __restrict__ W1, const float* __restrict__ W2, float* __restrict__ wt)
{
    int tid = blockIdx.x * blockDim.x + threadIdx.x;
    int stride = gridDim.x * blockDim.x;
    for (int n = tid; n < 64 * 20; n += stride) {
        int j = n & 63, k = n >> 6;
        wt[n] = W1[j * 20 + k];
    }
    for (int n = tid; n < 128 * 64; n += stride) {
        int o = n & 127, k = n >> 7;
        wt[1280 + n] = W2[o * 64 + k];
    }
}

// ============ K1: stats + percentiles + fused per-row MLP (wave/row) ============
// feats reference order (LDS sf slots):
// 0 mean, 1 std, 2 min, 3 max, 4 median, 5 trend, 6 ac1, 7 ac7, 8 ac24,
// 9 cv, 10 iqr, 11 seasonal, 12 skew, 13 kurt, 14 len, 15 sad, 16 madiff,
// 17 std_diff, 18 p25, 19 p75
__global__ __launch_bounds__(256) void fused_stats_mlp_kernel(
    const float* __restrict__ x, const float* __restrict__ wt,
    const float* __restrict__ b1, const float* __restrict__ b2,
    float* __restrict__ out, int nrows)
{
    __shared__ __align__(16) float sf[4][20];   // per-wave feature stash (wave-uniform)
    __shared__ __align__(16) float hsh[4][64];  // per-wave hidden layer

    const int gw   = (blockIdx.x * 256 + threadIdx.x) >> 6;  // row
    const int lane = threadIdx.x & 63;
    const int w    = (threadIdx.x >> 6);
    if (gw >= nrows) return;

    uvec32 a;
    const float* xr = x + (size_t)gw * S_LEN + lane * 32;
    #pragma unroll
    for (int q = 0; q < 8; q++) {
        float4 t = reinterpret_cast<const float4*>(xr)[q];
        a[4 * q + 0] = __float_as_uint(t.x); a[4 * q + 1] = __float_as_uint(t.y);
        a[4 * q + 2] = __float_as_uint(t.z); a[4 * q + 3] = __float_as_uint(t.w);
    }

    // ---------------- phase 1: streaming stats ----------------
    float s1 = 0.f, s2 = 0.f, sd2 = 0.f, sad = 0.f;
    float p1 = 0.f, p7 = 0.f, p24 = 0.f, se1 = 0.f, se2 = 0.f;
    float mn = VF(0), mx = VF(0);
    #pragma unroll
    for (int e = 0; e < 32; e++) {
        float val = VF(e);
        s1 += val; s2 = fmaf(val, val, s2);
        mn = fminf(mn, val); mx = fmaxf(mx, val);
    }
    #pragma unroll
    for (int e = 0; e < 31; e++) {
        float d = VF(e + 1) - VF(e);
        sd2 = fmaf(d, d, sd2); sad += fabsf(d);
        p1 = fmaf(VF(e), VF(e + 1), p1);
    }
    #pragma unroll
    for (int e = 0; e < 25; e++) p7 = fmaf(VF(e), VF(e + 7), p7);
    #pragma unroll
    for (int e = 0; e < 8; e++)  p24 = fmaf(VF(e), VF(e + 24), p24);

    const bool notlast = (lane < 63);
    #pragma unroll
    for (int j = 0; j < 24; j++) {
        float nb = __shfl_down(VF(j), 1, 64);
        float g = notlast ? nb : 0.f;
        p24 = fmaf(VF(8 + j), g, p24);
        if (j < 7) p7 = fmaf(VF(25 + j), g, p7);
        if (j == 0 && notlast) {
            float d = nb - VF(31);
            sd2 = fmaf(d, d, sd2); sad += fabsf(d);
            p1 = fmaf(VF(31), nb, p1);
        }
    }
    {   // seasonal x[::24]
        int r3 = lane % 3;
        float sv = (r3 == 0) ? VF(0) : ((r3 == 1) ? VF(16) : VF(8));
        se1 += sv; se2 = fmaf(sv, sv, se2);
        if (r3 == 0) { se1 += VF(24); se2 = fmaf(VF(24), VF(24), se2); }
    }
    // head/tail partials -> SGPRs
    float aa = 0, bb = 0, h7v = 0, hq7v = 0;
    #pragma unroll
    for (int e = 0; e < 24; e++) {
        aa += VF(e); bb = fmaf(VF(e), VF(e), bb);
        if (e == 6) { h7v = aa; hq7v = bb; }
    }
    float cc = 0, dd = 0, t7v = 0, tq7v = 0;
    #pragma unroll
    for (int e = 31; e >= 8; e--) {
        cc += VF(e); dd = fmaf(VF(e), VF(e), dd);
        if (e == 25) { t7v = cc; tq7v = dd; }
    }
    const float h1  = readlane_f(VF(0), 0),   t1  = readlane_f(VF(31), 63);
    const float h7  = readlane_f(h7v, 0),     hq7 = readlane_f(hq7v, 0);
    const float h24 = readlane_f(aa, 0),      hq24 = readlane_f(bb, 0);
    const float t7  = readlane_f(t7v, 63),    tq7 = readlane_f(tq7v, 63);
    const float t24 = readlane_f(cc, 63),     tq24 = readlane_f(dd, 63);
    const float hq1 = h1 * h1, tq1 = t1 * t1;

    float S1  = wred_add_f(s1);
    float mean = S1 * (1.0f / S_LEN);
    float S2  = wred_add_f(s2);
    float SD2 = wred_add_f(sd2);
    float SAD = wred_add_f(sad);
    float P1  = wred_add_f(p1);
    float P7  = wred_add_f(p7);
    float P24 = wred_add_f(p24);
    float SE1 = wred_add_f(se1);
    float SE2 = wred_add_f(se2);
    float MN  = wred_min_f(mn);
    float MX  = wred_max_f(mx);

    float c2 = 0.f, c3 = 0.f, c4 = 0.f;
    #pragma unroll
    for (int e = 0; e < 32; e++) {
        float xc = VF(e) - mean;
        float q = xc * xc;
        c2 += q; c3 = fmaf(q, xc, c3); c4 = fmaf(q, q, c4);
    }
    float C2 = wred_add_f(c2), C3 = wred_add_f(c3), C4 = wred_add_f(c4);

    // 16 stat features -> LDS stash NOW (frees registers across the select)
    {
        const float Sf = (float)S_LEN;
        const float nd = Sf - 1.0f;
        float m2v = C2 / Sf, m3v = C3 / Sf, m4v = C4 / Sf;
        float stdv = sqrtf(m2v);
        float dmean = (t1 - h1) / nd;
        float dvar = SD2 / nd - dmean * dmean;
        float std_diff = sqrtf(fmaxf(dvar, 0.f));
        float trend = std_diff / (stdv + EPS);
        float ac[3];
        const float Ls[3] = {1.f, 7.f, 24.f};
        const float Ps[3] = {P1, P7, P24};
        const float hd[3] = {h1, h7, h24},   hqv[3] = {hq1, hq7, hq24};
        const float tl[3] = {t1, t7, t24},   tqv[3] = {tq1, tq7, tq24};
        #pragma unroll
        for (int q = 0; q < 3; q++) {
            float n = Sf - Ls[q];
            float sa = S1 - tl[q], sb = S1 - hd[q];
            float qa = S2 - tqv[q], qb = S2 - hqv[q];
            float am = sa / n, bm = sb / n;
            float cov = Ps[q] / n - am * bm;
            float as_ = sqrtf(fmaxf(qa / n - am * am, 0.f));
            float bs_ = sqrtf(fmaxf(qb / n - bm * bm, 0.f));
            ac[q] = cov / (as_ * bs_);
        }
        float cv = stdv / (fabsf(mean) + EPS);
        float sm = SE1 / 86.f;
        float svar = SE2 / 86.f - sm * sm;
        float seasonal = svar / (m2v + EPS);
        float skew = m3v / (m2v * stdv);
        float kurt = m4v / (m2v * m2v) - 3.f;
        if (lane == 0) {
            float* s = sf[w];
            s[0]  = fin(mean);     s[1]  = fin(stdv);
            s[2]  = fin(MN);       s[3]  = fin(MX);
            s[5]  = fin(trend);    s[6]  = fin(ac[0]);
            s[7]  = fin(ac[1]);    s[8]  = fin(ac[2]);
            s[9]  = fin(cv);       s[11] = fin(seasonal);
            s[12] = fin(skew);     s[13] = fin(kurt);
            s[14] = Sf;            s[15] = fin(SAD);
            s[16] = fin(SAD / nd); s[17] = fin(std_diff);
        }
    }

    // ---------------- phase 2: bit-plane radix select ----------------
    #pragma unroll
    for (int e = 0; e < 32; e++) a[e] = f2o_bits(a[e]);
    transpose32(a);

    unsigned act0 = ~0u, act1 = ~0u, act2 = ~0u;
    int K0 = 511, K1 = 1023, K2 = 1535;
    unsigned uK0 = 0, uK1 = 0, uK2 = 0;
    #pragma unroll
    for (int b = 31; b >= 0; b--) {
        unsigned mb = a[31 - b];
        unsigned nmb = ~mb;
        unsigned z0 = act0 & nmb, z1 = act1 & nmb, z2 = act2 & nmb;
        int C01 = wred_add_i(__popc(z0) | (__popc(z1) << 16));
        int Cc2 = wred_add_i(__popc(z2));
        int c0 = C01 & 0xFFFF;
        int c1 = (int)((unsigned)C01 >> 16);
        if (K0 < c0)  act0 = z0; else { K0 -= c0;  act0 &= mb; uK0 |= (1u << b); }
        if (K1 < c1)  act1 = z1; else { K1 -= c1;  act1 &= mb; uK1 |= (1u << b); }
        if (K2 < Cc2) act2 = z2; else { K2 -= Cc2; act2 &= mb; uK2 |= (1u << b); }
    }
    int e01 = wred_add_i(__popc(act0) | (__popc(act1) << 16));
    int eq0 = e01 & 0xFFFF, eq1 = (int)((unsigned)e01 >> 16);
    int eq2 = wred_add_i(__popc(act2));

    transpose32(a);  // involution -> recover orderable values
    unsigned m0 = ~0u, m1 = ~0u, m2 = ~0u;
    #pragma unroll
    for (int e = 0; e < 32; e++) {
        unsigned ue = a[e];
        if (ue > uK0) m0 = m0 < ue ? m0 : ue;
        if (ue > uK1) m1 = m1 < ue ? m1 : ue;
        if (ue > uK2) m2 = m2 < ue ? m2 : ue;
    }
    m0 = wred_umin(m0); m1 = wred_umin(m1); m2 = wred_umin(m2);

    float v511 = o2f(uK0), v1023 = o2f(uK1), v1535 = o2f(uK2);
    float v512  = (K0 + 1 < eq0) ? v511  : o2f(m0);
    float v1024 = (K1 + 1 < eq1) ? v1023 : o2f(m1);
    float v1536 = (K2 + 1 < eq2) ? v1535 : o2f(m2);
    float p25 = v511 + 0.75f * (v512 - v511);
    float med = 0.5f * (v1023 + v1024);
    float p75 = v1535 + 0.25f * (v1536 - v1535);
    float iqr = p75 - p25;

    if (lane == 0) {
        float* s = sf[w];
        s[4]  = fin(med); s[10] = fin(iqr);
        s[18] = fin(p25); s[19] = fin(p75);
    }
    // Intra-wave LDS visibility: wave is lockstep, only a waitcnt is needed.
    __asm__ volatile("s_waitcnt lgkmcnt(0)" ::: "memory");
    __builtin_amdgcn_sched_barrier(0);

    // ---------------- phase 3: fused MLP (per row) ----------------
    // stage 1: h_j = relu(b1_j + sum_k f_k * W1T[k][j]), lane j in [0,64)
    const float* W1T = wt;            // [20][64]
    const float* W2T = wt + 1280;     // [64][128]
    const float4* sfv = (const float4*)sf[w];
    float4 f0 = sfv[0], f1 = sfv[1], f2 = sfv[2], f3 = sfv[3], f4 = sfv[4];
    float h = b1[lane];
    h = fmaf(f0.x, W1T[ 0 * 64 + lane], h);
    h = fmaf(f0.y, W1T[ 1 * 64 + lane], h);
    h = fmaf(f0.z, W1T[ 2 * 64 + lane], h);
    h = fmaf(f0.w, W1T[ 3 * 64 + lane], h);
    h = fmaf(f1.x, W1T[ 4 * 64 + lane], h);
    h = fmaf(f1.y, W1T[ 5 * 64 + lane], h);
    h = fmaf(f1.z, W1T[ 6 * 64 + lane], h);
    h = fmaf(f1.w, W1T[ 7 * 64 + lane], h);
    h = fmaf(f2.x, W1T[ 8 * 64 + lane], h);
    h = fmaf(f2.y, W1T[ 9 * 64 + lane], h);
    h = fmaf(f2.z, W1T[10 * 64 + lane], h);
    h = fmaf(f2.w, W1T[11 * 64 + lane], h);
    h = fmaf(f3.x, W1T[12 * 64 + lane], h);
    h = fmaf(f3.y, W1T[13 * 64 + lane], h);
    h = fmaf(f3.z, W1T[14 * 64 + lane], h);
    h = fmaf(f3.w, W1T[15 * 64 + lane], h);
    h = fmaf(f4.x, W1T[16 * 64 + lane], h);
    h = fmaf(f4.y, W1T[17 * 64 + lane], h);
    h = fmaf(f4.z, W1T[18 * 64 + lane], h);
    h = fmaf(f4.w, W1T[19 * 64 + lane], h);
    h = fmaxf(h, 0.f);
    hsh[w][lane] = h;
    __asm__ volatile("s_waitcnt lgkmcnt(0)" ::: "memory");
    __builtin_amdgcn_sched_barrier(0);

    // stage 2: lane j -> outputs 2j, 2j+1; h broadcast from LDS (b128, uniform addr)
    const int j2 = lane * 2;
    float2 b2v = *(const float2*)(b2 + j2);
    float acc0 = b2v.x, acc1 = b2v.y;
    const float4* hv4 = (const float4*)hsh[w];
    #pragma unroll
    for (int q = 0; q < 16; q++) {
        float4 hq = hv4[q];
        const float* wp = W2T + (4 * q) * 128 + j2;
        float2 w0 = *(const float2*)(wp);
        float2 w1 = *(const float2*)(wp + 128);
        float2 w2 = *(const float2*)(wp + 256);
        float2 w3 = *(const float2*)(wp + 384);
        acc0 = fmaf(hq.x, w0.x, acc0); acc1 = fmaf(hq.x, w0.y, acc1);
        acc0 = fmaf(hq.y, w1.x, acc0); acc1 = fmaf(hq.y, w1.y, acc1);
        acc0 = fmaf(hq.z, w2.x, acc0); acc1 = fmaf(hq.z, w2.y, acc1);
        acc0 = fmaf(hq.w, w3.x, acc0); acc1 = fmaf(hq.w, w3.y, acc1);
    }
    *(float2*)(out + (size_t)gw * 128 + j2) = make_float2(acc0, acc1);
}

extern "C" void kernel_launch(void* const* d_in, const int* in_sizes, int n_in,
                              void* d_out, int out_size, void* d_ws, size_t ws_size,
                              hipStream_t stream) {
    const float* x  = (const float*)d_in[0];
    const float* W1 = (const float*)d_in[1];
    const float* b1 = (const float*)d_in[2];
    const float* W2 = (const float*)d_in[3];
    const float* b2 = (const float*)d_in[4];
    float* out = (float*)d_out;
    float* wt  = (float*)d_ws;       // 9472 floats: W1T + W2T
    int nrows = in_sizes[0] / S_LEN;
    int blocks = (nrows + 3) / 4;    // wave per row
    transpose_w_kernel<<<8, 256, 0, stream>>>(W1, W2, wt);
    fused_stats_mlp_kernel<<<blocks, 256, 0, stream>>>(x, wt, b1, b2, out, nrows);
}

// Round 3
// 267.703 us; speedup vs baseline: 1.0523x; 1.0254x over previous
//
#include <hip/hip_runtime.h>
#include <cmath>

constexpr int S_LEN = 2048;
constexpr float EPS = 1e-8f;

typedef unsigned uvec32 __attribute__((ext_vector_type(32)));

__device__ __forceinline__ float fin(float v) { return isfinite(v) ? v : 0.0f; }
__device__ __forceinline__ float rcpf(float x) { return __builtin_amdgcn_rcpf(x); }

__device__ __forceinline__ unsigned f2o_bits(unsigned u) {
    return (u & 0x80000000u) ? ~u : (u | 0x80000000u);
}
__device__ __forceinline__ float o2f(unsigned u) {
    return __uint_as_float((u & 0x80000000u) ? (u ^ 0x80000000u) : ~u);
}

// ---- DPP helpers (ctrl/rmask are ICEs via template params) ----
template <int Ctrl, int Rmask>
__device__ __forceinline__ int dpp_zero_i(int x) {
    return __builtin_amdgcn_update_dpp(0, x, Ctrl, Rmask, 0xF, true);
}
template <int Ctrl>
__device__ __forceinline__ int dpp_keep_i(int x) {
    return __builtin_amdgcn_update_dpp(x, x, Ctrl, 0xF, 0xF, false);
}
__device__ __forceinline__ int wred_add_i(int v) {
    v += dpp_zero_i<0xB1, 0xF>(v);
    v += dpp_zero_i<0x4E, 0xF>(v);
    v += dpp_zero_i<0x114, 0xF>(v);
    v += dpp_zero_i<0x118, 0xF>(v);
    v += dpp_zero_i<0x142, 0xA>(v);
    v += dpp_zero_i<0x143, 0xC>(v);
    return __builtin_amdgcn_readlane(v, 63);
}
__device__ __forceinline__ float wred_add_f(float v) {
    #define ADDF(CT, RM) v += __uint_as_float((unsigned)dpp_zero_i<CT, RM>((int)__float_as_uint(v)))
    ADDF(0xB1, 0xF); ADDF(0x4E, 0xF); ADDF(0x114, 0xF);
    ADDF(0x118, 0xF); ADDF(0x142, 0xA); ADDF(0x143, 0xC);
    #undef ADDF
    return __uint_as_float((unsigned)__builtin_amdgcn_readlane((int)__float_as_uint(v), 63));
}
__device__ __forceinline__ float wred_min_f(float v) {
    #define MINF(CT) v = fminf(v, __uint_as_float((unsigned)dpp_keep_i<CT>((int)__float_as_uint(v))))
    MINF(0xB1); MINF(0x4E); MINF(0x114); MINF(0x118); MINF(0x142); MINF(0x143);
    #undef MINF
    return __uint_as_float((unsigned)__builtin_amdgcn_readlane((int)__float_as_uint(v), 63));
}
__device__ __forceinline__ float wred_max_f(float v) {
    #define MAXF(CT) v = fmaxf(v, __uint_as_float((unsigned)dpp_keep_i<CT>((int)__float_as_uint(v))))
    MAXF(0xB1); MAXF(0x4E); MAXF(0x114); MAXF(0x118); MAXF(0x142); MAXF(0x143);
    #undef MAXF
    return __uint_as_float((unsigned)__builtin_amdgcn_readlane((int)__float_as_uint(v), 63));
}
__device__ __forceinline__ unsigned wred_umin(unsigned v) {
    #define MINU(CT) { unsigned t = (unsigned)dpp_keep_i<CT>((int)v); v = v < t ? v : t; }
    MINU(0xB1) MINU(0x4E) MINU(0x114) MINU(0x118) MINU(0x142) MINU(0x143)
    #undef MINU
    return (unsigned)__builtin_amdgcn_readlane((int)v, 63);
}
__device__ __forceinline__ float readlane_f(float x, int l) {
    return __uint_as_float((unsigned)__builtin_amdgcn_readlane((int)__float_as_uint(x), l));
}

// Hacker's Delight 32x32 bit transpose (anti-diagonal; involution).
// Stages j=16, j=8 use v_perm_b32 (byte-exact equivalent of the xor-shift
// form, derived: j=16: A[k]'=[a3 a2 b3 b2], A[k|16]'=[a1 a0 b1 b0];
// j=8: A[k]'=[a3 b3 a1 b1], A[k|8]'=[a2 b2 a0 b0]; src0 bytes=4..7, src1=0..3).
__device__ __forceinline__ void transpose32(uvec32& A) {
    #pragma unroll
    for (int k = 0; k < 16; k++) {
        unsigned lo = __builtin_amdgcn_perm(A[k], A[k + 16], 0x07060302u);
        unsigned hi = __builtin_amdgcn_perm(A[k], A[k + 16], 0x05040100u);
        A[k] = lo; A[k + 16] = hi;
    }
    #pragma unroll
    for (int k0 = 0; k0 < 32; k0 += 16) {
        #pragma unroll
        for (int k = k0; k < k0 + 8; k++) {
            unsigned lo = __builtin_amdgcn_perm(A[k], A[k + 8], 0x07030501u);
            unsigned hi = __builtin_amdgcn_perm(A[k], A[k + 8], 0x06020400u);
            A[k] = lo; A[k + 8] = hi;
        }
    }
    #pragma unroll
    for (int j = 4; j; j >>= 1) {
        unsigned m = (j == 4) ? 0x0F0F0F0Fu : (j == 2) ? 0x33333333u : 0x55555555u;
        #pragma unroll
        for (int k = 0; k < 32; k++) {
            if (!(k & j)) {
                unsigned t = (A[k] ^ (A[k | j] >> j)) & m;
                A[k] = A[k] ^ t;
                A[k | j] = A[k | j] ^ (t << j);
            }
        }
    }
}

#define VF(e) __uint_as_float(a[e])

// ============ K0: transpose W1 once into d_ws ============
// wt[0:1280) = W1T (20 x 64): W1T[k*64+j] = W1[j*20+k]
__global__ __launch_bounds__(256) void transpose_w_kernel(
    const float* __restrict__ W1, float* __restrict__ wt)
{
    int tid = blockIdx.x * blockDim.x + threadIdx.x;
    int stride = gridDim.x * blockDim.x;
    for (int n = tid; n < 64 * 20; n += stride) {
        int j = n & 63, k = n >> 6;
        wt[n] = W1[j * 20 + k];
    }
}

// ============ K1: stats + percentiles + fused per-row MLP (wave/row) ============
// feats order (LDS sf slots): 0 mean, 1 std, 2 min, 3 max, 4 median, 5 trend,
// 6 ac1, 7 ac7, 8 ac24, 9 cv, 10 iqr, 11 seasonal, 12 skew, 13 kurt, 14 len,
// 15 sad, 16 madiff, 17 std_diff, 18 p25, 19 p75
__global__ __launch_bounds__(256, 4) void fused_stats_mlp_kernel(
    const float* __restrict__ x, const float* __restrict__ wt,
    const float* __restrict__ b1, const float* __restrict__ W2,
    const float* __restrict__ b2, float* __restrict__ out, int nrows)
{
    __shared__ __align__(16) float sf[4][20];   // per-wave feature stash (wave-uniform)
    __shared__ __align__(16) float hsh[4][64];  // per-wave hidden layer

    const int gw   = (blockIdx.x * 256 + threadIdx.x) >> 6;  // row
    const int lane = threadIdx.x & 63;
    const int w    = (threadIdx.x >> 6);
    if (gw >= nrows) return;

    uvec32 a;
    const float* xr = x + (size_t)gw * S_LEN + lane * 32;
    #pragma unroll
    for (int q = 0; q < 8; q++) {
        float4 t = reinterpret_cast<const float4*>(xr)[q];
        a[4 * q + 0] = __float_as_uint(t.x); a[4 * q + 1] = __float_as_uint(t.y);
        a[4 * q + 2] = __float_as_uint(t.z); a[4 * q + 3] = __float_as_uint(t.w);
    }

    // ---------------- phase 1: streaming stats ----------------
    float s1 = 0.f, s2 = 0.f, sd2 = 0.f, sad = 0.f;
    float p1 = 0.f, p7 = 0.f, p24 = 0.f, se1 = 0.f, se2 = 0.f;
    float mn = VF(0), mx = VF(0);
    #pragma unroll
    for (int e = 0; e < 32; e++) {
        float val = VF(e);
        s1 += val; s2 = fmaf(val, val, s2);
        mn = fminf(mn, val); mx = fmaxf(mx, val);
    }
    #pragma unroll
    for (int e = 0; e < 31; e++) {
        float d = VF(e + 1) - VF(e);
        sd2 = fmaf(d, d, sd2); sad += fabsf(d);
        p1 = fmaf(VF(e), VF(e + 1), p1);
    }
    #pragma unroll
    for (int e = 0; e < 25; e++) p7 = fmaf(VF(e), VF(e + 7), p7);
    #pragma unroll
    for (int e = 0; e < 8; e++)  p24 = fmaf(VF(e), VF(e + 24), p24);

    const bool notlast = (lane < 63);
    #pragma unroll
    for (int j = 0; j < 24; j++) {
        float nb = __shfl_down(VF(j), 1, 64);
        float g = notlast ? nb : 0.f;
        p24 = fmaf(VF(8 + j), g, p24);
        if (j < 7) p7 = fmaf(VF(25 + j), g, p7);
        if (j == 0 && notlast) {
            float d = nb - VF(31);
            sd2 = fmaf(d, d, sd2); sad += fabsf(d);
            p1 = fmaf(VF(31), nb, p1);
        }
    }
    {   // seasonal x[::24]
        int r3 = lane % 3;
        float sv = (r3 == 0) ? VF(0) : ((r3 == 1) ? VF(16) : VF(8));
        se1 += sv; se2 = fmaf(sv, sv, se2);
        if (r3 == 0) { se1 += VF(24); se2 = fmaf(VF(24), VF(24), se2); }
    }
    // head/tail partials -> SGPRs
    float aa = 0, bb = 0, h7v = 0, hq7v = 0;
    #pragma unroll
    for (int e = 0; e < 24; e++) {
        aa += VF(e); bb = fmaf(VF(e), VF(e), bb);
        if (e == 6) { h7v = aa; hq7v = bb; }
    }
    float cc = 0, dd = 0, t7v = 0, tq7v = 0;
    #pragma unroll
    for (int e = 31; e >= 8; e--) {
        cc += VF(e); dd = fmaf(VF(e), VF(e), dd);
        if (e == 25) { t7v = cc; tq7v = dd; }
    }
    const float h1  = readlane_f(VF(0), 0),   t1  = readlane_f(VF(31), 63);
    const float h7  = readlane_f(h7v, 0),     hq7 = readlane_f(hq7v, 0);
    const float h24 = readlane_f(aa, 0),      hq24 = readlane_f(bb, 0);
    const float t7  = readlane_f(t7v, 63),    tq7 = readlane_f(tq7v, 63);
    const float t24 = readlane_f(cc, 63),     tq24 = readlane_f(dd, 63);
    const float hq1 = h1 * h1, tq1 = t1 * t1;

    float S1  = wred_add_f(s1);
    float mean = S1 * (1.0f / S_LEN);
    float S2  = wred_add_f(s2);
    float SD2 = wred_add_f(sd2);
    float SAD = wred_add_f(sad);
    float P1  = wred_add_f(p1);
    float P7  = wred_add_f(p7);
    float P24 = wred_add_f(p24);
    float SE1 = wred_add_f(se1);
    float SE2 = wred_add_f(se2);
    float MN  = wred_min_f(mn);
    float MX  = wred_max_f(mx);

    float c2 = 0.f, c3 = 0.f, c4 = 0.f;
    #pragma unroll
    for (int e = 0; e < 32; e++) {
        float xc = VF(e) - mean;
        float q = xc * xc;
        c2 += q; c3 = fmaf(q, xc, c3); c4 = fmaf(q, q, c4);
    }
    float C2 = wred_add_f(c2), C3 = wred_add_f(c3), C4 = wred_add_f(c4);

    // 16 stat features -> LDS stash NOW (frees registers across the select)
    {
        constexpr float invS  = 1.0f / 2048.0f;   // exact (pow2)
        constexpr float invND = 1.0f / 2047.0f;
        const float Sf = (float)S_LEN;
        float m2v = C2 * invS, m3v = C3 * invS, m4v = C4 * invS;
        float stdv = sqrtf(m2v);
        float dmean = (t1 - h1) * invND;
        float dvar = SD2 * invND - dmean * dmean;
        float std_diff = sqrtf(fmaxf(dvar, 0.f));
        float trend = std_diff * rcpf(stdv + EPS);
        float ac[3];
        const float invN[3] = {1.0f / 2047.0f, 1.0f / 2041.0f, 1.0f / 2024.0f};
        const float Ps[3] = {P1, P7, P24};
        const float hd[3] = {h1, h7, h24},   hqv[3] = {hq1, hq7, hq24};
        const float tl[3] = {t1, t7, t24},   tqv[3] = {tq1, tq7, tq24};
        #pragma unroll
        for (int q = 0; q < 3; q++) {
            float in = invN[q];
            float sa = S1 - tl[q], sb = S1 - hd[q];
            float qa = S2 - tqv[q], qb = S2 - hqv[q];
            float am = sa * in, bm = sb * in;
            float cov = Ps[q] * in - am * bm;
            float as_ = sqrtf(fmaxf(qa * in - am * am, 0.f));
            float bs_ = sqrtf(fmaxf(qb * in - bm * bm, 0.f));
            ac[q] = cov * rcpf(as_ * bs_);
        }
        float cv = stdv * rcpf(fabsf(mean) + EPS);
        float sm = SE1 * (1.0f / 86.0f);
        float svar = SE2 * (1.0f / 86.0f) - sm * sm;
        float seasonal = svar * rcpf(m2v + EPS);
        float skew = m3v * rcpf(m2v * stdv);
        float kurt = m4v * rcpf(m2v * m2v) - 3.f;
        if (lane == 0) {
            float* s = sf[w];
            s[0]  = fin(mean);     s[1]  = fin(stdv);
            s[2]  = fin(MN);       s[3]  = fin(MX);
            s[5]  = fin(trend);    s[6]  = fin(ac[0]);
            s[7]  = fin(ac[1]);    s[8]  = fin(ac[2]);
            s[9]  = fin(cv);       s[11] = fin(seasonal);
            s[12] = fin(skew);     s[13] = fin(kurt);
            s[14] = Sf;            s[15] = fin(SAD);
            s[16] = fin(SAD * invND); s[17] = fin(std_diff);
        }
    }

    // ---------------- phase 2: bit-plane radix select ----------------
    #pragma unroll
    for (int e = 0; e < 32; e++) a[e] = f2o_bits(a[e]);
    transpose32(a);

    // Count ONES (w = act & plane); zeros = cnt - ones; cnt tracked in scalars.
    unsigned act0 = ~0u, act1 = ~0u, act2 = ~0u;
    int K0 = 511, K1 = 1023, K2 = 1535;
    int cnt0 = 2048, cnt1 = 2048, cnt2 = 2048;
    unsigned uK0 = 0, uK1 = 0, uK2 = 0;
    #pragma unroll
    for (int b = 31; b >= 0; b--) {
        unsigned mb = a[31 - b];
        unsigned w0 = act0 & mb, w1 = act1 & mb, w2 = act2 & mb;
        int O01 = wred_add_i(__popc(w0) | (__popc(w1) << 16));
        int O2  = wred_add_i(__popc(w2));
        int c0 = cnt0 - (O01 & 0xFFFF);
        int c1 = cnt1 - (int)((unsigned)O01 >> 16);
        int c2i = cnt2 - O2;
        if (K0 < c0)  { act0 ^= w0; cnt0 = c0; }  else { K0 -= c0;  act0 = w0; cnt0 -= c0;  uK0 |= (1u << b); }
        if (K1 < c1)  { act1 ^= w1; cnt1 = c1; }  else { K1 -= c1;  act1 = w1; cnt1 -= c1;  uK1 |= (1u << b); }
        if (K2 < c2i) { act2 ^= w2; cnt2 = c2i; } else { K2 -= c2i; act2 = w2; cnt2 -= c2i; uK2 |= (1u << b); }
    }
    // After bit 0, act marks exactly the elements equal to uK: eq == cnt.
    const int eq0 = cnt0, eq1 = cnt1, eq2 = cnt2;

    transpose32(a);  // involution -> recover orderable values
    // min over {ue > uK} via wrap-around: ue - (uK+1) is small iff ue > uK.
    const unsigned k0p1 = uK0 + 1, k1p1 = uK1 + 1, k2p1 = uK2 + 1;
    unsigned m0 = ~0u, m1 = ~0u, m2 = ~0u;
    #pragma unroll
    for (int e = 0; e < 32; e++) {
        unsigned ue = a[e];
        unsigned d0 = ue - k0p1; m0 = m0 < d0 ? m0 : d0;
        unsigned d1 = ue - k1p1; m1 = m1 < d1 ? m1 : d1;
        unsigned d2 = ue - k2p1; m2 = m2 < d2 ? m2 : d2;
    }
    m0 = wred_umin(m0) + k0p1;
    m1 = wred_umin(m1) + k1p1;
    m2 = wred_umin(m2) + k2p1;

    float v511 = o2f(uK0), v1023 = o2f(uK1), v1535 = o2f(uK2);
    float v512  = (K0 + 1 < eq0) ? v511  : o2f(m0);
    float v1024 = (K1 + 1 < eq1) ? v1023 : o2f(m1);
    float v1536 = (K2 + 1 < eq2) ? v1535 : o2f(m2);
    float p25 = v511 + 0.75f * (v512 - v511);
    float med = 0.5f * (v1023 + v1024);
    float p75 = v1535 + 0.25f * (v1536 - v1535);
    float iqr = p75 - p25;

    if (lane == 0) {
        float* s = sf[w];
        s[4]  = fin(med); s[10] = fin(iqr);
        s[18] = fin(p25); s[19] = fin(p75);
    }
    // Intra-wave LDS visibility: wave is lockstep, only a waitcnt is needed.
    __asm__ volatile("s_waitcnt lgkmcnt(0)" ::: "memory");
    __builtin_amdgcn_sched_barrier(0);

    // ---------------- phase 3: fused MLP (per row) ----------------
    // stage 1: h_j = relu(b1_j + sum_k f_k * W1T[k][j]), lane j in [0,64)
    const float* W1T = wt;            // [20][64]
    const float4* sfv = (const float4*)sf[w];
    float4 f0 = sfv[0], f1 = sfv[1], f2 = sfv[2], f3 = sfv[3], f4 = sfv[4];
    float h = b1[lane];
    h = fmaf(f0.x, W1T[ 0 * 64 + lane], h);
    h = fmaf(f0.y, W1T[ 1 * 64 + lane], h);
    h = fmaf(f0.z, W1T[ 2 * 64 + lane], h);
    h = fmaf(f0.w, W1T[ 3 * 64 + lane], h);
    h = fmaf(f1.x, W1T[ 4 * 64 + lane], h);
    h = fmaf(f1.y, W1T[ 5 * 64 + lane], h);
    h = fmaf(f1.z, W1T[ 6 * 64 + lane], h);
    h = fmaf(f1.w, W1T[ 7 * 64 + lane], h);
    h = fmaf(f2.x, W1T[ 8 * 64 + lane], h);
    h = fmaf(f2.y, W1T[ 9 * 64 + lane], h);
    h = fmaf(f2.z, W1T[10 * 64 + lane], h);
    h = fmaf(f2.w, W1T[11 * 64 + lane], h);
    h = fmaf(f3.x, W1T[12 * 64 + lane], h);
    h = fmaf(f3.y, W1T[13 * 64 + lane], h);
    h = fmaf(f3.z, W1T[14 * 64 + lane], h);
    h = fmaf(f3.w, W1T[15 * 64 + lane], h);
    h = fmaf(f4.x, W1T[16 * 64 + lane], h);
    h = fmaf(f4.y, W1T[17 * 64 + lane], h);
    h = fmaf(f4.z, W1T[18 * 64 + lane], h);
    h = fmaf(f4.w, W1T[19 * 64 + lane], h);
    h = fmaxf(h, 0.f);
    hsh[w][lane] = h;
    __asm__ volatile("s_waitcnt lgkmcnt(0)" ::: "memory");
    __builtin_amdgcn_sched_barrier(0);

    // stage 2: lane j -> outputs 2j, 2j+1 via direct row-major W2 float4 reads
    const int j2 = lane * 2;
    float2 b2v = *(const float2*)(b2 + j2);
    float acc0 = b2v.x, acc1 = b2v.y;
    const float4* w2r0 = (const float4*)(W2 + (size_t)j2 * 64);
    const float4* w2r1 = (const float4*)(W2 + (size_t)(j2 + 1) * 64);
    const float4* hv4 = (const float4*)hsh[w];
    #pragma unroll
    for (int q = 0; q < 16; q++) {
        float4 hq = hv4[q];
        float4 wa = w2r0[q];
        float4 wb = w2r1[q];
        acc0 = fmaf(hq.x, wa.x, acc0); acc1 = fmaf(hq.x, wb.x, acc1);
        acc0 = fmaf(hq.y, wa.y, acc0); acc1 = fmaf(hq.y, wb.y, acc1);
        acc0 = fmaf(hq.z, wa.z, acc0); acc1 = fmaf(hq.z, wb.z, acc1);
        acc0 = fmaf(hq.w, wa.w, acc0); acc1 = fmaf(hq.w, wb.w, acc1);
    }
    *(float2*)(out + (size_t)gw * 128 + j2) = make_float2(acc0, acc1);
}

extern "C" void kernel_launch(void* const* d_in, const int* in_sizes, int n_in,
                              void* d_out, int out_size, void* d_ws, size_t ws_size,
                              hipStream_t stream) {
    const float* x  = (const float*)d_in[0];
    const float* W1 = (const float*)d_in[1];
    const float* b1 = (const float*)d_in[2];
    const float* W2 = (const float*)d_in[3];
    const float* b2 = (const float*)d_in[4];
    float* out = (float*)d_out;
    float* wt  = (float*)d_ws;       // 1280 floats: W1T
    int nrows = in_sizes[0] / S_LEN;
    int blocks = (nrows + 3) / 4;    // wave per row
    transpose_w_kernel<<<2, 256, 0, stream>>>(W1, wt);
    fused_stats_mlp_kernel<<<blocks, 256, 0, stream>>>(x, wt, b1, W2, b2, out, nrows);
}